// Round 1
// baseline (104.254 us; speedup 1.0000x reference)
//
#include <hip/hip_runtime.h>

// FWHT over last axis of 8192x8192 fp32. One row per 256-thread block.
// 13 butterfly stages split: 5 in-register (bits 0,1,10,11,12) ->
// LDS exchange -> 5 in-register (bits 2..6) -> LDS exchange ->
// 3 in-register (bits 7,8,9). XOR-swizzled LDS (float4 cells) keeps every
// access <=2-way bank conflict (free). Loads/stores fully coalesced float4.

#define ROW_N 8192

__global__ __launch_bounds__(256) void fwht8192_kernel(const float* __restrict__ in,
                                                       float* __restrict__ out) {
    __shared__ __align__(16) float lds[ROW_N];  // 32 KiB
    const int t = threadIdx.x;                  // 0..255
    const size_t row = blockIdx.x;
    const float* __restrict__ src = in + row * (size_t)ROW_N;
    float* __restrict__ dst = out + row * (size_t)ROW_N;

    // ---- Load layout A: a[j][c] = x[c + 4t + 1024j]  (coalesced float4) ----
    float a[8][4];
#pragma unroll
    for (int j = 0; j < 8; ++j) {
        const float4 v = *reinterpret_cast<const float4*>(src + 4 * t + 1024 * j);
        a[j][0] = v.x; a[j][1] = v.y; a[j][2] = v.z; a[j][3] = v.w;
    }

    // ---- P1a: butterflies on bits 0,1 (within float4) ----
#pragma unroll
    for (int j = 0; j < 8; ++j) {
        float s0 = a[j][0] + a[j][1], d0 = a[j][0] - a[j][1];
        float s1 = a[j][2] + a[j][3], d1 = a[j][2] - a[j][3];
        a[j][0] = s0 + s1; a[j][1] = d0 + d1;
        a[j][2] = s0 - s1; a[j][3] = d0 - d1;
    }
    // ---- P1b: butterflies on bits 10,11,12 (across j regs) ----
#pragma unroll
    for (int h = 1; h < 8; h <<= 1) {
#pragma unroll
        for (int j = 0; j < 8; ++j) {
            if (!(j & h)) {
#pragma unroll
                for (int c = 0; c < 4; ++c) {
                    float p = a[j][c], q = a[j + h][c];
                    a[j][c] = p + q; a[j + h][c] = p - q;
                }
            }
        }
    }

    // ---- X1 write: float4 cell = t + 256j, swizzled sc = cell ^ ((cell>>5)&7) ----
#pragma unroll
    for (int j = 0; j < 8; ++j) {
        const int cell = t + 256 * j;
        const int sc = cell ^ ((cell >> 5) & 7);
        *reinterpret_cast<float4*>(lds + 4 * sc) =
            make_float4(a[j][0], a[j][1], a[j][2], a[j][3]);
    }
    __syncthreads();

    // ---- X1 read: layout B, element idx = (t&3) + 4u + 128*(t>>2), u=0..31 ----
    const int q  = t >> 2;   // 0..63 -> idx bits 7..12
    const int c0 = t & 3;    // idx bits 0,1
    const int xq = q & 7;    // swizzle key
    float v[32];
#pragma unroll
    for (int u = 0; u < 32; ++u) {
        v[u] = lds[4 * ((u ^ xq) + 32 * q) + c0];  // 2-way bank conflict (free)
    }

    // ---- P2: butterflies on bits 2..6 (across u) ----
#pragma unroll
    for (int h = 1; h < 32; h <<= 1) {
#pragma unroll
        for (int u = 0; u < 32; ++u) {
            if (!(u & h)) {
                float p = v[u], r = v[u + h];
                v[u] = p + r; v[u + h] = p - r;
            }
        }
    }

    // ---- X2 write-back to the SAME addresses (owner-exclusive, no barrier before) ----
#pragma unroll
    for (int u = 0; u < 32; ++u) {
        lds[4 * ((u ^ xq) + 32 * q) + c0] = v[u];
    }
    __syncthreads();

    // ---- X2 read: layout C, float4 cell r4 = (t&31) + 32p + 256*(t>>5) ----
    const int tl = t & 31;   // idx bits 2..6
    const int th = t >> 5;   // idx bits 10..12
    float b[8][4];
#pragma unroll
    for (int p = 0; p < 8; ++p) {
        const int sc = (tl ^ p) + 32 * p + 256 * th;  // r4 ^ ((r4>>5)&7)
        const float4 w = *reinterpret_cast<const float4*>(lds + 4 * sc);
        b[p][0] = w.x; b[p][1] = w.y; b[p][2] = w.z; b[p][3] = w.w;
    }

    // ---- P3: butterflies on bits 7,8,9 (across p regs) ----
#pragma unroll
    for (int h = 1; h < 8; h <<= 1) {
#pragma unroll
        for (int p = 0; p < 8; ++p) {
            if (!(p & h)) {
#pragma unroll
                for (int c = 0; c < 4; ++c) {
                    float x = b[p][c], y = b[p + h][c];
                    b[p][c] = x + y; b[p + h][c] = x - y;
                }
            }
        }
    }

    // ---- Store: idx = c + 4*(t&31) + 128p + 1024*(t>>5) -> 2x512B contiguous/instr ----
#pragma unroll
    for (int p = 0; p < 8; ++p) {
        *reinterpret_cast<float4*>(dst + 4 * tl + 128 * p + 1024 * th) =
            make_float4(b[p][0], b[p][1], b[p][2], b[p][3]);
    }
}

extern "C" void kernel_launch(void* const* d_in, const int* in_sizes, int n_in,
                              void* d_out, int out_size, void* d_ws, size_t ws_size,
                              hipStream_t stream) {
    const float* x = (const float*)d_in[0];
    float* y = (float*)d_out;
    (void)in_sizes; (void)n_in; (void)out_size; (void)d_ws; (void)ws_size;
    fwht8192_kernel<<<dim3(8192), dim3(256), 0, stream>>>(x, y);
}

// Round 2
// 84.531 us; speedup vs baseline: 1.2333x; 1.2333x over previous
//
#include <hip/hip_runtime.h>

// FWHT over last axis of 8192x8192 fp32. One row per 256-thread block.
// 13 butterfly stages split: 5 in-register (bits 0,1,10,11,12) ->
// LDS exchange -> 5 in-register (bits 2..6) -> LDS exchange ->
// 3 in-register (bits 7,8,9). XOR-swizzled LDS (float4 cells) keeps every
// access <=2-way bank conflict (free). Loads/stores fully coalesced float4.
//
// R1 change: output stores are NON-TEMPORAL (global_store_dwordx4 nt) so the
// 256 MiB write stream does not allocate in the 256 MiB Infinity Cache; the
// input (exactly 256 MiB) can then stay L3-resident across graph replays,
// cutting HBM FETCH traffic.

#define ROW_N 8192

typedef float f32x4 __attribute__((ext_vector_type(4)));

__global__ __launch_bounds__(256) void fwht8192_kernel(const float* __restrict__ in,
                                                       float* __restrict__ out) {
    __shared__ __align__(16) float lds[ROW_N];  // 32 KiB
    const int t = threadIdx.x;                  // 0..255
    const size_t row = blockIdx.x;
    const float* __restrict__ src = in + row * (size_t)ROW_N;
    float* __restrict__ dst = out + row * (size_t)ROW_N;

    // ---- Load layout A: a[j][c] = x[c + 4t + 1024j]  (coalesced float4) ----
    float a[8][4];
#pragma unroll
    for (int j = 0; j < 8; ++j) {
        const float4 v = *reinterpret_cast<const float4*>(src + 4 * t + 1024 * j);
        a[j][0] = v.x; a[j][1] = v.y; a[j][2] = v.z; a[j][3] = v.w;
    }

    // ---- P1a: butterflies on bits 0,1 (within float4) ----
#pragma unroll
    for (int j = 0; j < 8; ++j) {
        float s0 = a[j][0] + a[j][1], d0 = a[j][0] - a[j][1];
        float s1 = a[j][2] + a[j][3], d1 = a[j][2] - a[j][3];
        a[j][0] = s0 + s1; a[j][1] = d0 + d1;
        a[j][2] = s0 - s1; a[j][3] = d0 - d1;
    }
    // ---- P1b: butterflies on bits 10,11,12 (across j regs) ----
#pragma unroll
    for (int h = 1; h < 8; h <<= 1) {
#pragma unroll
        for (int j = 0; j < 8; ++j) {
            if (!(j & h)) {
#pragma unroll
                for (int c = 0; c < 4; ++c) {
                    float p = a[j][c], q = a[j + h][c];
                    a[j][c] = p + q; a[j + h][c] = p - q;
                }
            }
        }
    }

    // ---- X1 write: float4 cell = t + 256j, swizzled sc = cell ^ ((cell>>5)&7) ----
#pragma unroll
    for (int j = 0; j < 8; ++j) {
        const int cell = t + 256 * j;
        const int sc = cell ^ ((cell >> 5) & 7);
        *reinterpret_cast<float4*>(lds + 4 * sc) =
            make_float4(a[j][0], a[j][1], a[j][2], a[j][3]);
    }
    __syncthreads();

    // ---- X1 read: layout B, element idx = (t&3) + 4u + 128*(t>>2), u=0..31 ----
    const int q  = t >> 2;   // 0..63 -> idx bits 7..12
    const int c0 = t & 3;    // idx bits 0,1
    const int xq = q & 7;    // swizzle key
    float v[32];
#pragma unroll
    for (int u = 0; u < 32; ++u) {
        v[u] = lds[4 * ((u ^ xq) + 32 * q) + c0];  // 2-way bank conflict (free)
    }

    // ---- P2: butterflies on bits 2..6 (across u) ----
#pragma unroll
    for (int h = 1; h < 32; h <<= 1) {
#pragma unroll
        for (int u = 0; u < 32; ++u) {
            if (!(u & h)) {
                float p = v[u], r = v[u + h];
                v[u] = p + r; v[u + h] = p - r;
            }
        }
    }

    // ---- X2 write-back to the SAME addresses (owner-exclusive, no barrier before) ----
#pragma unroll
    for (int u = 0; u < 32; ++u) {
        lds[4 * ((u ^ xq) + 32 * q) + c0] = v[u];
    }
    __syncthreads();

    // ---- X2 read: layout C, float4 cell r4 = (t&31) + 32p + 256*(t>>5) ----
    const int tl = t & 31;   // idx bits 2..6
    const int th = t >> 5;   // idx bits 10..12
    float b[8][4];
#pragma unroll
    for (int p = 0; p < 8; ++p) {
        const int sc = (tl ^ p) + 32 * p + 256 * th;  // r4 ^ ((r4>>5)&7)
        const float4 w = *reinterpret_cast<const float4*>(lds + 4 * sc);
        b[p][0] = w.x; b[p][1] = w.y; b[p][2] = w.z; b[p][3] = w.w;
    }

    // ---- P3: butterflies on bits 7,8,9 (across p regs) ----
#pragma unroll
    for (int h = 1; h < 8; h <<= 1) {
#pragma unroll
        for (int p = 0; p < 8; ++p) {
            if (!(p & h)) {
#pragma unroll
                for (int c = 0; c < 4; ++c) {
                    float x = b[p][c], y = b[p + h][c];
                    b[p][c] = x + y; b[p + h][c] = x - y;
                }
            }
        }
    }

    // ---- Store (non-temporal): idx = c + 4*(t&31) + 128p + 1024*(t>>5) ----
#pragma unroll
    for (int p = 0; p < 8; ++p) {
        f32x4 w;
        w.x = b[p][0]; w.y = b[p][1]; w.z = b[p][2]; w.w = b[p][3];
        __builtin_nontemporal_store(
            w, reinterpret_cast<f32x4*>(dst + 4 * tl + 128 * p + 1024 * th));
    }
}

extern "C" void kernel_launch(void* const* d_in, const int* in_sizes, int n_in,
                              void* d_out, int out_size, void* d_ws, size_t ws_size,
                              hipStream_t stream) {
    const float* x = (const float*)d_in[0];
    float* y = (float*)d_out;
    (void)in_sizes; (void)n_in; (void)out_size; (void)d_ws; (void)ws_size;
    fwht8192_kernel<<<dim3(8192), dim3(256), 0, stream>>>(x, y);
}